// Round 9
// baseline (741.952 us; speedup 1.0000x reference)
//
#include <hip/hip_runtime.h>
#include <cstdint>
#include <cstddef>

#define SS 4096
#define HH 16
#define BH 64   // B*H

typedef unsigned short bfu;
typedef __attribute__((ext_vector_type(8))) short short8;
typedef __attribute__((ext_vector_type(4))) float f32x4;

__device__ __forceinline__ float bf2f(bfu u) { return __uint_as_float(((unsigned)u) << 16); }
__device__ __forceinline__ bfu f2bf(float f) {
    unsigned u = __float_as_uint(f);
    return (bfu)((u + 0x7fffu + ((u >> 16) & 1u)) >> 16);
}
union BF8 { uint4 u4; bfu h[8]; short8 s8; };

__device__ __forceinline__ unsigned encf(float x) {
    unsigned u = __float_as_uint(x);
    return (u & 0x80000000u) ? ~u : (u | 0x80000000u);
}
__device__ __forceinline__ float decf(unsigned u) {
    return (u & 0x80000000u) ? __uint_as_float(u & 0x7fffffffu) : __uint_as_float(~u);
}

__device__ __forceinline__ void gload_lds16(const bfu* g, bfu* l) {
    __builtin_amdgcn_global_load_lds(
        (const __attribute__((address_space(1))) void*)g,
        (__attribute__((address_space(3))) void*)l,
        16, 0, 0);
}

__global__ void diag_kernel(float* __restrict__ out, float val, int n) {
    int i = blockIdx.x * 256 + threadIdx.x;
    if (i < n) out[i] = val;
}

// ---------------- f32 -> bf16 elementwise (x) ----------------
__global__ __launch_bounds__(256) void f32_to_bf16_kernel(
    const float* __restrict__ in, bfu* __restrict__ out, int n8)
{
    int t = blockIdx.x * 256 + threadIdx.x;
    if (t >= n8) return;
    float4 a = reinterpret_cast<const float4*>(in)[(size_t)t * 2];
    float4 b = reinterpret_cast<const float4*>(in)[(size_t)t * 2 + 1];
    BF8 p;
    p.h[0] = f2bf(a.x); p.h[1] = f2bf(a.y); p.h[2] = f2bf(a.z); p.h[3] = f2bf(a.w);
    p.h[4] = f2bf(b.x); p.h[5] = f2bf(b.y); p.h[6] = f2bf(b.z); p.h[7] = f2bf(b.w);
    reinterpret_cast<uint4*>(out)[t] = p.u4;
}

// ---------------- 1024x1024 f32 [K][N] -> bf16 [N][K] transpose ----------------
__global__ __launch_bounds__(256) void transpose_w_kernel(
    const float* __restrict__ src, bfu* __restrict__ dst)
{
    __shared__ float t[32][33];
    int tx = threadIdx.x & 31, ty = threadIdx.x >> 5;   // 32x8
    int n0 = blockIdx.x * 32, k0 = blockIdx.y * 32;
    #pragma unroll
    for (int i = 0; i < 4; i++)
        t[ty + 8 * i][tx] = src[(size_t)(k0 + ty + 8 * i) * 1024 + n0 + tx];
    __syncthreads();
    #pragma unroll
    for (int i = 0; i < 4; i++)
        dst[(size_t)(n0 + ty + 8 * i) * 1024 + k0 + tx] = f2bf(t[tx][ty + 8 * i]);
}

// ---------------- MFMA QKV GEMM: A[16384][1024] @ Bt[3072][1024]^T -> q,k,v bf16 ----------------
__global__ __launch_bounds__(256) void gemm_qkv_mfma(
    const bfu* __restrict__ A, const bfu* __restrict__ Bt,
    const float* __restrict__ bq, const float* __restrict__ bk, const float* __restrict__ bv,
    bfu* __restrict__ q, bfu* __restrict__ k, bfu* __restrict__ v)
{
    __shared__ __align__(16) bfu As[128 * 32];
    __shared__ __align__(16) bfu Bs[128 * 32];
    int tid = threadIdx.x;
    int w = tid >> 6, lane = tid & 63;
    int row0 = blockIdx.y * 128;
    int col0 = blockIdx.x * 128;

    int srow = lane >> 2;
    int scg  = lane & 3;

    f32x4 acc[4][4];
    #pragma unroll
    for (int i = 0; i < 4; i++)
        #pragma unroll
        for (int j = 0; j < 4; j++)
            acc[i][j] = (f32x4){0.f, 0.f, 0.f, 0.f};

    int wm = (w >> 1) * 64, wn = (w & 1) * 64;
    int l15 = lane & 15, lk = lane >> 4;

    for (int k0 = 0; k0 < 1024; k0 += 32) {
        #pragma unroll
        for (int i = 0; i < 2; i++) {
            int r = w * 32 + i * 16 + srow;
            int cg = scg ^ ((r >> 1) & 3);
            gload_lds16(A  + (size_t)(row0 + r) * 1024 + k0 + cg * 8, &As[(w * 32 + i * 16) * 32]);
            gload_lds16(Bt + (size_t)(col0 + r) * 1024 + k0 + cg * 8, &Bs[(w * 32 + i * 16) * 32]);
        }
        __syncthreads();
        short8 a[4], b[4];
        #pragma unroll
        for (int mi = 0; mi < 4; mi++) {
            int r = wm + mi * 16 + l15;
            int cs = lk ^ ((r >> 1) & 3);
            a[mi] = *reinterpret_cast<const short8*>(&As[r * 32 + cs * 8]);
        }
        #pragma unroll
        for (int ni = 0; ni < 4; ni++) {
            int r = wn + ni * 16 + l15;
            int cs = lk ^ ((r >> 1) & 3);
            b[ni] = *reinterpret_cast<const short8*>(&Bs[r * 32 + cs * 8]);
        }
        #pragma unroll
        for (int mi = 0; mi < 4; mi++)
            #pragma unroll
            for (int ni = 0; ni < 4; ni++)
                acc[mi][ni] = __builtin_amdgcn_mfma_f32_16x16x32_bf16(a[mi], b[ni], acc[mi][ni], 0, 0, 0);
        __syncthreads();
    }

    int tsel = col0 >> 10;
    const float* bias = tsel == 0 ? bq : (tsel == 1 ? bk : bv);
    bfu* Out          = tsel == 0 ? q  : (tsel == 1 ? k  : v);
    float scale = tsel == 0 ? 0.125f : 1.0f;
    #pragma unroll
    for (int ni = 0; ni < 4; ni++) {
        int nl = (col0 & 1023) + wn + ni * 16 + l15;
        float bb = bias[nl];
        int h = nl >> 6, dh = nl & 63;
        #pragma unroll
        for (int mi = 0; mi < 4; mi++) {
            #pragma unroll
            for (int r = 0; r < 4; r++) {
                int row = row0 + wm + mi * 16 + lk * 4 + r;
                int bI = row >> 12, s = row & 4095;
                Out[((size_t)(bI * HH + h) * SS + s) * 64 + dh] = f2bf((acc[mi][ni][r] + bb) * scale);
            }
        }
    }
}

// ---------------- MFMA output GEMM: yA[16384][1024] @ Wot[1024][1024]^T -> out f32 ----------------
__global__ __launch_bounds__(256) void gemm_out_mfma(
    const bfu* __restrict__ A, const bfu* __restrict__ Bt,
    const float* __restrict__ bo, float* __restrict__ out)
{
    __shared__ __align__(16) bfu As[128 * 32];
    __shared__ __align__(16) bfu Bs[128 * 32];
    int tid = threadIdx.x;
    int w = tid >> 6, lane = tid & 63;
    int row0 = blockIdx.y * 128;
    int col0 = blockIdx.x * 128;
    int srow = lane >> 2, scg = lane & 3;

    f32x4 acc[4][4];
    #pragma unroll
    for (int i = 0; i < 4; i++)
        #pragma unroll
        for (int j = 0; j < 4; j++)
            acc[i][j] = (f32x4){0.f, 0.f, 0.f, 0.f};

    int wm = (w >> 1) * 64, wn = (w & 1) * 64;
    int l15 = lane & 15, lk = lane >> 4;

    for (int k0 = 0; k0 < 1024; k0 += 32) {
        #pragma unroll
        for (int i = 0; i < 2; i++) {
            int r = w * 32 + i * 16 + srow;
            int cg = scg ^ ((r >> 1) & 3);
            gload_lds16(A  + (size_t)(row0 + r) * 1024 + k0 + cg * 8, &As[(w * 32 + i * 16) * 32]);
            gload_lds16(Bt + (size_t)(col0 + r) * 1024 + k0 + cg * 8, &Bs[(w * 32 + i * 16) * 32]);
        }
        __syncthreads();
        short8 a[4], b[4];
        #pragma unroll
        for (int mi = 0; mi < 4; mi++) {
            int r = wm + mi * 16 + l15;
            int cs = lk ^ ((r >> 1) & 3);
            a[mi] = *reinterpret_cast<const short8*>(&As[r * 32 + cs * 8]);
        }
        #pragma unroll
        for (int ni = 0; ni < 4; ni++) {
            int r = wn + ni * 16 + l15;
            int cs = lk ^ ((r >> 1) & 3);
            b[ni] = *reinterpret_cast<const short8*>(&Bs[r * 32 + cs * 8]);
        }
        #pragma unroll
        for (int mi = 0; mi < 4; mi++)
            #pragma unroll
            for (int ni = 0; ni < 4; ni++)
                acc[mi][ni] = __builtin_amdgcn_mfma_f32_16x16x32_bf16(a[mi], b[ni], acc[mi][ni], 0, 0, 0);
        __syncthreads();
    }

    #pragma unroll
    for (int ni = 0; ni < 4; ni++) {
        int n = col0 + wn + ni * 16 + l15;
        float bb = bo[n];
        #pragma unroll
        for (int mi = 0; mi < 4; mi++) {
            #pragma unroll
            for (int r = 0; r < 4; r++) {
                int row = row0 + wm + mi * 16 + lk * 4 + r;
                out[(size_t)row * 1024 + n] = acc[mi][ni][r] + bb;
            }
        }
    }
}

// ---------------- all-level coarsen: one block = 64 full-res rows -> levels 1..6 ----------------
__global__ __launch_bounds__(256) void coarsen_all_kernel(
    const bfu* __restrict__ qi, const bfu* __restrict__ ki, const bfu* __restrict__ vi,
    bfu* __restrict__ qc, bfu* __restrict__ kc, bfu* __restrict__ vc)
{
    int bid = blockIdx.x;              // sel*4096 + bh*64 + g0
    int sel = bid >> 12;
    int bh = (bid >> 6) & 63;
    int g0 = bid & 63;
    const bfu* in = sel == 0 ? qi : (sel == 1 ? ki : vi);
    bfu* outb     = sel == 0 ? qc : (sel == 1 ? kc : vc);
    __shared__ float bufA[64][64];
    __shared__ float bufB[32][64];
    int tid = threadIdx.x;
    const bfu* src = in + ((size_t)bh * SS + g0 * 64) * 64;
    for (int idx = tid; idx < 64 * 8; idx += 256) {
        int r = idx >> 3, c8 = (idx & 7) * 8;
        BF8 a; a.u4 = *reinterpret_cast<const uint4*>(src + (size_t)r * 64 + c8);
        #pragma unroll
        for (int t = 0; t < 8; t++) bufA[r][c8 + t] = bf2f(a.h[t]);
    }
    __syncthreads();
    const size_t GOFFc[7] = {0, 0, 8388608, 12582912, 14680064, 15728640, 16252928};
    #pragma unroll
    for (int l = 1; l <= 6; l++) {
        int nr = 64 >> l;
        float (*s)[64]   = (l & 1) ? bufA : (float(*)[64])bufB;
        float (*dst)[64] = (l & 1) ? (float(*)[64])bufB : bufA;
        for (int idx = tid; idx < nr * 64; idx += 256) {
            int r = idx >> 6, d = idx & 63;
            float m = 0.5f * (s[2 * r][d] + s[2 * r + 1][d]);
            dst[r][d] = m;
            size_t off = GOFFc[l] + ((size_t)bh * (SS >> l) + g0 * nr + r) * 64 + d;
            outb[off] = f2bf(m);
        }
        __syncthreads();
    }
}

// ---------------- unified max pass: level 0 + all levels, no sim storage ----------------
__global__ __launch_bounds__(256) void maxpass_kernel(
    const bfu* __restrict__ q, const bfu* __restrict__ k,
    const bfu* __restrict__ qc, const bfu* __restrict__ kc,
    const float* __restrict__ rpb, unsigned* __restrict__ m_enc)
{
    const size_t GOFF[7] = {0, 0, 8388608, 12582912, 14680064, 15728640, 16252928};
    int bid = blockIdx.x;
    const bfu *qb, *kb;
    const float* rp;
    int boff, bh;
    if (bid < 8192) {
        int blk = bid & 127; bh = bid >> 7;
        qb = q + ((size_t)bh * SS + blk * 32) * 64;
        kb = k + ((size_t)bh * SS + blk * 32) * 64;
        rp = rpb; boff = 63;
    } else {
        int rem = bid - 8192;
        int l = 1, cnt = 4096;
        while (rem >= cnt) { rem -= cnt; l++; cnt >>= 1; }
        int p = 64 >> l, rows = SS >> l;
        int g2 = rem % (2 * p); bh = rem / (2 * p);
        int dir = g2 & 1, g = g2 >> 1;
        qb = qc + GOFF[l] + ((size_t)bh * rows + g * 64 + dir * 32) * 64;
        kb = kc + GOFF[l] + ((size_t)bh * rows + g * 64 + (1 - dir) * 32) * 64;
        rp = rpb + (size_t)l * 127 * 16;
        boff = dir ? 31 : 95;
    }
    int h = bh & 15;
    __shared__ float qs[32][65], ks[32][65];
    int tid = threadIdx.x;
    {
        int r = tid >> 3, c8 = (tid & 7) * 8;
        BF8 a; a.u4 = *reinterpret_cast<const uint4*>(qb + (size_t)r * 64 + c8);
        BF8 b; b.u4 = *reinterpret_cast<const uint4*>(kb + (size_t)r * 64 + c8);
        #pragma unroll
        for (int t = 0; t < 8; t++) { qs[r][c8 + t] = bf2f(a.h[t]); ks[r][c8 + t] = bf2f(b.h[t]); }
    }
    __syncthreads();
    int j = tid & 31, i4 = tid >> 5;
    float acc[4] = {0.f, 0.f, 0.f, 0.f};
    for (int d = 0; d < 64; d++) {
        float kv = ks[j][d];
        #pragma unroll
        for (int ii = 0; ii < 4; ii++) acc[ii] += qs[i4 * 4 + ii][d] * kv;
    }
    float lmax = -1e30f;
    #pragma unroll
    for (int ii = 0; ii < 4; ii++) {
        int i = i4 * 4 + ii;
        lmax = fmaxf(lmax, acc[ii] + rp[((j - i) + boff) * 16 + h]);
    }
    for (int off = 32; off > 0; off >>= 1) lmax = fmaxf(lmax, __shfl_down(lmax, off));
    __shared__ float wm[4];
    if ((tid & 63) == 0) wm[tid >> 6] = lmax;
    __syncthreads();
    if (tid == 0) {
        float m2 = fmaxf(fmaxf(wm[0], wm[1]), fmaxf(wm[2], wm[3]));
        atomicMax(&m_enc[bh], encf(m2));
    }
}

// ---------------- all levels: recompute sim + exp + coarse PV -> yc/zc ----------------
__global__ __launch_bounds__(256) void pvcall_kernel(
    const bfu* __restrict__ qc, const bfu* __restrict__ kc, const bfu* __restrict__ vc,
    const float* __restrict__ rpb, const unsigned* __restrict__ m_enc,
    float* __restrict__ yc1, float* __restrict__ ycB, float* __restrict__ zcb)
{
    const size_t GOFF[7] = {0, 0, 8388608, 12582912, 14680064, 15728640, 16252928};
    const size_t YO[7]   = {0, 0, 0, 4194304, 6291456, 7340032, 7864320};
    const size_t ZO[7]   = {0, 0, 131072, 196608, 229376, 245760, 253952};
    int bid = blockIdx.x;              // 8064 blocks
    int rem = bid;
    int l = 1, cnt = 4096;
    while (rem >= cnt) { rem -= cnt; l++; cnt >>= 1; }
    int p = 64 >> l, rows = SS >> l;
    int g2 = rem % (2 * p); int bh = rem / (2 * p);
    int dir = g2 & 1, g = g2 >> 1;
    int h = bh & 15;
    float m = 3.0f * decf(m_enc[bh]);
    const bfu* qb = qc + GOFF[l] + ((size_t)bh * rows + g * 64 + dir * 32) * 64;
    const bfu* kb = kc + GOFF[l] + ((size_t)bh * rows + g * 64 + (1 - dir) * 32) * 64;
    const bfu* vb = vc + GOFF[l] + ((size_t)bh * rows + g * 64 + (1 - dir) * 32) * 64;
    const float* rp = rpb + (size_t)l * 127 * 16;
    int boff = dir ? 31 : 95;
    float* yc = (l == 1) ? (yc1 + (size_t)bh * 2048 * 64)
                         : (ycB + YO[l] + (size_t)bh * rows * 64);
    float* zc = zcb + ZO[l] + (size_t)bh * rows;

    __shared__ float qs[32][65], ks[32][65], vs[32][65];
    __shared__ float ps[32][33];
    int tid = threadIdx.x;
    {
        int r = tid >> 3, c8 = (tid & 7) * 8;
        BF8 a; a.u4 = *reinterpret_cast<const uint4*>(qb + (size_t)r * 64 + c8);
        BF8 b; b.u4 = *reinterpret_cast<const uint4*>(kb + (size_t)r * 64 + c8);
        BF8 c; c.u4 = *reinterpret_cast<const uint4*>(vb + (size_t)r * 64 + c8);
        #pragma unroll
        for (int t = 0; t < 8; t++) {
            qs[r][c8 + t] = bf2f(a.h[t]); ks[r][c8 + t] = bf2f(b.h[t]); vs[r][c8 + t] = bf2f(c.h[t]);
        }
    }
    __syncthreads();
    int j = tid & 31, i4 = tid >> 5;
    {
        float acc[4] = {0.f, 0.f, 0.f, 0.f};
        for (int d = 0; d < 64; d++) {
            float kv = ks[j][d];
            #pragma unroll
            for (int ii = 0; ii < 4; ii++) acc[ii] += qs[i4 * 4 + ii][d] * kv;
        }
        #pragma unroll
        for (int ii = 0; ii < 4; ii++) {
            int i = i4 * 4 + ii;
            ps[i][j] = expf(acc[ii] + rp[((j - i) + boff) * 16 + h] - m);
        }
    }
    __syncthreads();
    if (tid < 32) {
        float zs = 0.f;
        #pragma unroll
        for (int jj = 0; jj < 32; jj++) zs += ps[tid][jj];
        int cr = g * 64 + dir * 32 + tid;
        zc[cr] = zs;
    }
    int d = tid & 63, i0 = tid >> 6;
    #pragma unroll
    for (int ii = 0; ii < 8; ii++) {
        int i = ii * 4 + i0;
        float a = 0.f;
        #pragma unroll
        for (int jj = 0; jj < 32; jj++) a += ps[i][jj] * vs[jj][d];
        int cr = g * 64 + dir * 32 + i;
        yc[(size_t)cr * 64 + d] = a;
    }
}

// ---------------- fused: sim0 recompute + level-0 PV + coarse gather + normalize -> bf16 A ----------------
__global__ __launch_bounds__(256) void gather_kernel(
    const bfu* __restrict__ q, const bfu* __restrict__ k, const bfu* __restrict__ v,
    const float* __restrict__ rpb, const unsigned* __restrict__ m_enc,
    const float* __restrict__ yc1, const float* __restrict__ ycB,
    const float* __restrict__ zcb, bfu* __restrict__ yA)
{
    int bid = blockIdx.x;
    int blk = bid & 127, bh = bid >> 7;
    int h = bh & 15;
    float m = 3.0f * decf(m_enc[bh]);
    __shared__ float qs[32][65], ks[32][65], vs[32][65];
    __shared__ float ps[32][33];
    __shared__ float ycL[32][64];
    __shared__ float zcL[32];
    __shared__ float zrow[32];
    int tid = threadIdx.x;
    {
        const bfu* qb = q + ((size_t)bh * SS + blk * 32) * 64;
        const bfu* kb = k + ((size_t)bh * SS + blk * 32) * 64;
        const bfu* vb = v + ((size_t)bh * SS + blk * 32) * 64;
        int r = tid >> 3, c8 = (tid & 7) * 8;
        BF8 a; a.u4 = *reinterpret_cast<const uint4*>(qb + (size_t)r * 64 + c8);
        BF8 b; b.u4 = *reinterpret_cast<const uint4*>(kb + (size_t)r * 64 + c8);
        BF8 c; c.u4 = *reinterpret_cast<const uint4*>(vb + (size_t)r * 64 + c8);
        #pragma unroll
        for (int t = 0; t < 8; t++) {
            qs[r][c8 + t] = bf2f(a.h[t]); ks[r][c8 + t] = bf2f(b.h[t]); vs[r][c8 + t] = bf2f(c.h[t]);
        }
    }
    // stage coarse rows for all 6 levels
    const float* ybase[6];
    ybase[0] = yc1 + (size_t)bh * 2048 * 64;
    ybase[1] = ycB + 0       + (size_t)bh * 1024 * 64;
    ybase[2] = ycB + 4194304 + (size_t)bh * 512 * 64;
    ybase[3] = ycB + 6291456 + (size_t)bh * 256 * 64;
    ybase[4] = ycB + 7340032 + (size_t)bh * 128 * 64;
    ybase[5] = ycB + 7864320 + (size_t)bh * 64 * 64;
    const float* zbase[6];
    zbase[0] = zcb + 0      + (size_t)bh * 2048;
    zbase[1] = zcb + 131072 + (size_t)bh * 1024;
    zbase[2] = zcb + 196608 + (size_t)bh * 512;
    zbase[3] = zcb + 229376 + (size_t)bh * 256;
    zbase[4] = zcb + 245760 + (size_t)bh * 128;
    zbase[5] = zcb + 253952 + (size_t)bh * 64;
    const int Pl[6] = {0, 16, 24, 28, 30, 31};
    const int nl[6] = {16, 8, 4, 2, 1, 1};
    #pragma unroll
    for (int l = 1; l <= 6; l++) {
        int base_cr = (blk * 32) >> l;
        int cnt = nl[l - 1] * 64;
        for (int idx = tid; idx < cnt; idx += 256) {
            int rr = idx >> 6, dd = idx & 63;
            ycL[Pl[l - 1] + rr][dd] = ybase[l - 1][(size_t)(base_cr + rr) * 64 + dd];
        }
        if (tid < nl[l - 1]) zcL[Pl[l - 1] + tid] = zbase[l - 1][base_cr + tid];
    }
    __syncthreads();
    int j = tid & 31, i4 = tid >> 5;
    {
        float acc[4] = {0.f, 0.f, 0.f, 0.f};
        for (int d = 0; d < 64; d++) {
            float kv = ks[j][d];
            #pragma unroll
            for (int ii = 0; ii < 4; ii++) acc[ii] += qs[i4 * 4 + ii][d] * kv;
        }
        #pragma unroll
        for (int ii = 0; ii < 4; ii++) {
            int i = i4 * 4 + ii;
            ps[i][j] = expf(acc[ii] + rpb[((j - i) + 63) * 16 + h] - m);
        }
    }
    __syncthreads();
    const int Pl2[6] = {0, 16, 24, 28, 30, 31};
    if (tid < 32) {
        float zs = 0.f;
        #pragma unroll
        for (int jj = 0; jj < 32; jj++) zs += ps[tid][jj];
        #pragma unroll
        for (int l = 1; l <= 6; l++) zs += zcL[Pl2[l - 1] + (tid >> l)];
        zrow[tid] = 1.0f / zs;
    }
    __syncthreads();
    int d = tid & 63, i0 = tid >> 6;
    int b = bh >> 4, s0 = blk * 32;
    #pragma unroll
    for (int ii = 0; ii < 8; ii++) {
        int i = ii * 4 + i0;
        float a = 0.f;
        #pragma unroll
        for (int jj = 0; jj < 32; jj++) a += ps[i][jj] * vs[jj][d];
        #pragma unroll
        for (int l = 1; l <= 6; l++) a += ycL[Pl2[l - 1] + (i >> l)][d];
        a *= zrow[i];
        yA[((size_t)(b * SS + s0 + i)) * 1024 + h * 64 + d] = f2bf(a);
    }
}

extern "C" void kernel_launch(void* const* d_in, const int* in_sizes, int n_in,
                              void* d_out, int out_size, void* d_ws, size_t ws_size,
                              hipStream_t stream)
{
    const float* x   = (const float*)d_in[0];
    const float* wq  = (const float*)d_in[1];
    const float* bq  = (const float*)d_in[2];
    const float* wk  = (const float*)d_in[3];
    const float* bk  = (const float*)d_in[4];
    const float* wv  = (const float*)d_in[5];
    const float* bv  = (const float*)d_in[6];
    const float* rpb = (const float*)d_in[7];
    const float* wo  = (const float*)d_in[8];
    const float* bo  = (const float*)d_in[9];
    float* out = (float*)d_out;

    const size_t NEED = 267387392ULL;   // 255.0 MiB
    if (ws_size < NEED) {
        float val = (float)(ws_size >> 20);
        int n = out_size;
        hipLaunchKernelGGL(diag_kernel, dim3((n + 255) / 256), dim3(256), 0, stream, out, val, n);
        return;
    }

    char* w8 = (char*)d_ws;
    // live full pipeline:
    bfu* q    = (bfu*)(w8);                        // 32 MiB (read until gather)
    bfu* k    = (bfu*)(w8 + 33554432);             // 32 MiB (read until gather)
    bfu* v    = (bfu*)(w8 + 67108864);             // 32 MiB (read until gather)
    bfu* qc   = (bfu*)(w8 + 100663296);            // 31.5 MiB (dead after pvcall) -> yA
    bfu* kc   = (bfu*)(w8 + 133693440);            // 31.5 MiB (dead after pvcall)
    bfu* vc   = (bfu*)(w8 + 166723584);            // 31.5 MiB (dead after pvcall) -> wot
    // region A (w8+199753728, 32 MiB): xbf during stages 1-2; ycB + zcb afterwards
    // region B (w8+233308160, 31.5 MiB + old-zbuf 1 MiB): wqkv_t during stages 1-2; yc1 afterwards
    unsigned* m_enc = (unsigned*)(w8 + 267386880);
    bfu*   xbf    = (bfu*)(w8 + 199753728);
    bfu*   wqkv_t = (bfu*)(w8 + 233308160);
    float* ycB    = (float*)(w8 + 199753728);      // 32,505,856 B (levels 2-6)
    float* zcb    = (float*)(w8 + 232259584);      //  1,048,576 B
    float* yc1    = (float*)(w8 + 233308160);      // 33,554,432 B (level 1)
    bfu*   yA     = qc;                            // over dead qc (32 MiB fits qc+kc slots)
    bfu*   wot    = vc;                            // over dead vc (2 MiB)

    // 1. bf16 conversions: x, transposed weights [N][K]
    hipLaunchKernelGGL(f32_to_bf16_kernel, dim3(8192), dim3(256), 0, stream, x, xbf, 2097152);
    hipLaunchKernelGGL(transpose_w_kernel, dim3(32, 32), dim3(256), 0, stream, wq, wqkv_t);
    hipLaunchKernelGGL(transpose_w_kernel, dim3(32, 32), dim3(256), 0, stream, wk, wqkv_t + 1048576);
    hipLaunchKernelGGL(transpose_w_kernel, dim3(32, 32), dim3(256), 0, stream, wv, wqkv_t + 2097152);

    // 2. QKV projection (bf16 MFMA)
    hipLaunchKernelGGL(gemm_qkv_mfma, dim3(24, 128), dim3(256), 0, stream,
                       xbf, wqkv_t, bq, bk, bv, q, k, v);

    // 3. coarsen pyramid — single launch, all levels
    hipLaunchKernelGGL(coarsen_all_kernel, dim3(12288), dim3(256), 0, stream, q, k, v, qc, kc, vc);

    // 4. global max over all levels (no sim storage)
    hipMemsetAsync(m_enc, 0, 64 * sizeof(unsigned), stream);
    hipLaunchKernelGGL(maxpass_kernel, dim3(16256), dim3(256), 0, stream, q, k, qc, kc, rpb, m_enc);

    // 5. all-level fused sim-recompute + PV -> coarse yc/zc (one launch)
    hipLaunchKernelGGL(pvcall_kernel, dim3(8064), dim3(256), 0, stream,
                       qc, kc, vc, rpb, m_enc, yc1, ycB, zcb);

    // 6. transpose Wo into dead vc slot
    hipLaunchKernelGGL(transpose_w_kernel, dim3(32, 32), dim3(256), 0, stream, wo, wot);

    // 7. fused sim0-recompute + level-0 PV + gather + normalize -> bf16 A (over dead qc)
    hipLaunchKernelGGL(gather_kernel, dim3(8192), dim3(256), 0, stream,
                       q, k, v, rpb, m_enc, yc1, ycB, zcb, yA);

    // 8. output projection (bf16 MFMA)
    hipLaunchKernelGGL(gemm_out_mfma, dim3(8, 128), dim3(256), 0, stream, yA, wot, bo, out);
}

// Round 10
// 544.664 us; speedup vs baseline: 1.3622x; 1.3622x over previous
//
#include <hip/hip_runtime.h>
#include <cstdint>
#include <cstddef>

#define SS 4096
#define HH 16
#define BH 64   // B*H

typedef unsigned short bfu;
typedef __attribute__((ext_vector_type(8))) short short8;
typedef __attribute__((ext_vector_type(4))) float f32x4;

__device__ __forceinline__ float bf2f(bfu u) { return __uint_as_float(((unsigned)u) << 16); }
__device__ __forceinline__ bfu f2bf(float f) {
    unsigned u = __float_as_uint(f);
    return (bfu)((u + 0x7fffu + ((u >> 16) & 1u)) >> 16);
}
union BF8 { uint4 u4; bfu h[8]; short8 s8; };

__device__ __forceinline__ unsigned encf(float x) {
    unsigned u = __float_as_uint(x);
    return (u & 0x80000000u) ? ~u : (u | 0x80000000u);
}
__device__ __forceinline__ float decf(unsigned u) {
    return (u & 0x80000000u) ? __uint_as_float(u & 0x7fffffffu) : __uint_as_float(~u);
}

__device__ __forceinline__ void gload_lds16(const bfu* g, bfu* l) {
    __builtin_amdgcn_global_load_lds(
        (const __attribute__((address_space(1))) void*)g,
        (__attribute__((address_space(3))) void*)l,
        16, 0, 0);
}

__global__ void diag_kernel(float* __restrict__ out, float val, int n) {
    int i = blockIdx.x * 256 + threadIdx.x;
    if (i < n) out[i] = val;
}

// ---------------- f32 -> bf16 elementwise (x) ----------------
__global__ __launch_bounds__(256) void f32_to_bf16_kernel(
    const float* __restrict__ in, bfu* __restrict__ out, int n8)
{
    int t = blockIdx.x * 256 + threadIdx.x;
    if (t >= n8) return;
    float4 a = reinterpret_cast<const float4*>(in)[(size_t)t * 2];
    float4 b = reinterpret_cast<const float4*>(in)[(size_t)t * 2 + 1];
    BF8 p;
    p.h[0] = f2bf(a.x); p.h[1] = f2bf(a.y); p.h[2] = f2bf(a.z); p.h[3] = f2bf(a.w);
    p.h[4] = f2bf(b.x); p.h[5] = f2bf(b.y); p.h[6] = f2bf(b.z); p.h[7] = f2bf(b.w);
    reinterpret_cast<uint4*>(out)[t] = p.u4;
}

// ---------------- 1024x1024 f32 [K][N] -> bf16 [N][K] transpose ----------------
__global__ __launch_bounds__(256) void transpose_w_kernel(
    const float* __restrict__ src, bfu* __restrict__ dst)
{
    __shared__ float t[32][33];
    int tx = threadIdx.x & 31, ty = threadIdx.x >> 5;   // 32x8
    int n0 = blockIdx.x * 32, k0 = blockIdx.y * 32;
    #pragma unroll
    for (int i = 0; i < 4; i++)
        t[ty + 8 * i][tx] = src[(size_t)(k0 + ty + 8 * i) * 1024 + n0 + tx];
    __syncthreads();
    #pragma unroll
    for (int i = 0; i < 4; i++)
        dst[(size_t)(n0 + ty + 8 * i) * 1024 + k0 + tx] = f2bf(t[tx][ty + 8 * i]);
}

// ---------------- MFMA QKV GEMM: writes q,k row-major and V TRANSPOSED (vT[bh][d][s]) ----------------
__global__ __launch_bounds__(256) void gemm_qkv_mfma(
    const bfu* __restrict__ A, const bfu* __restrict__ Bt,
    const float* __restrict__ bq, const float* __restrict__ bk, const float* __restrict__ bv,
    bfu* __restrict__ q, bfu* __restrict__ k, bfu* __restrict__ vt)
{
    __shared__ __align__(16) bfu As[128 * 32];
    __shared__ __align__(16) bfu Bs[128 * 32];
    int tid = threadIdx.x;
    int w = tid >> 6, lane = tid & 63;
    int row0 = blockIdx.y * 128;
    int col0 = blockIdx.x * 128;

    int srow = lane >> 2;
    int scg  = lane & 3;

    f32x4 acc[4][4];
    #pragma unroll
    for (int i = 0; i < 4; i++)
        #pragma unroll
        for (int j = 0; j < 4; j++)
            acc[i][j] = (f32x4){0.f, 0.f, 0.f, 0.f};

    int wm = (w >> 1) * 64, wn = (w & 1) * 64;
    int l15 = lane & 15, lk = lane >> 4;

    for (int k0 = 0; k0 < 1024; k0 += 32) {
        #pragma unroll
        for (int i = 0; i < 2; i++) {
            int r = w * 32 + i * 16 + srow;
            int cg = scg ^ ((r >> 1) & 3);
            gload_lds16(A  + (size_t)(row0 + r) * 1024 + k0 + cg * 8, &As[(w * 32 + i * 16) * 32]);
            gload_lds16(Bt + (size_t)(col0 + r) * 1024 + k0 + cg * 8, &Bs[(w * 32 + i * 16) * 32]);
        }
        __syncthreads();
        short8 a[4], b[4];
        #pragma unroll
        for (int mi = 0; mi < 4; mi++) {
            int r = wm + mi * 16 + l15;
            int cs = lk ^ ((r >> 1) & 3);
            a[mi] = *reinterpret_cast<const short8*>(&As[r * 32 + cs * 8]);
        }
        #pragma unroll
        for (int ni = 0; ni < 4; ni++) {
            int r = wn + ni * 16 + l15;
            int cs = lk ^ ((r >> 1) & 3);
            b[ni] = *reinterpret_cast<const short8*>(&Bs[r * 32 + cs * 8]);
        }
        #pragma unroll
        for (int mi = 0; mi < 4; mi++)
            #pragma unroll
            for (int ni = 0; ni < 4; ni++)
                acc[mi][ni] = __builtin_amdgcn_mfma_f32_16x16x32_bf16(a[mi], b[ni], acc[mi][ni], 0, 0, 0);
        __syncthreads();
    }

    int tsel = col0 >> 10;
    if (tsel == 2) {
        #pragma unroll
        for (int ni = 0; ni < 4; ni++) {
            int nl = (col0 & 1023) + wn + ni * 16 + l15;
            float bb = bv[nl];
            int h = nl >> 6, dh = nl & 63;
            #pragma unroll
            for (int mi = 0; mi < 4; mi++) {
                #pragma unroll
                for (int r = 0; r < 4; r++) {
                    int row = row0 + wm + mi * 16 + lk * 4 + r;
                    int bI = row >> 12, s = row & 4095;
                    vt[(((size_t)(bI * HH + h)) * 64 + dh) * (size_t)SS + s] = f2bf(acc[mi][ni][r] + bb);
                }
            }
        }
    } else {
        const float* bias = tsel == 0 ? bq : bk;
        bfu* Out          = tsel == 0 ? q  : k;
        float scale = tsel == 0 ? 0.125f : 1.0f;
        #pragma unroll
        for (int ni = 0; ni < 4; ni++) {
            int nl = (col0 & 1023) + wn + ni * 16 + l15;
            float bb = bias[nl];
            int h = nl >> 6, dh = nl & 63;
            #pragma unroll
            for (int mi = 0; mi < 4; mi++) {
                #pragma unroll
                for (int r = 0; r < 4; r++) {
                    int row = row0 + wm + mi * 16 + lk * 4 + r;
                    int bI = row >> 12, s = row & 4095;
                    Out[((size_t)(bI * HH + h) * SS + s) * 64 + dh] = f2bf((acc[mi][ni][r] + bb) * scale);
                }
            }
        }
    }
}

// ---------------- MFMA output GEMM: yA[16384][1024] @ Wot[1024][1024]^T -> out f32 ----------------
__global__ __launch_bounds__(256) void gemm_out_mfma(
    const bfu* __restrict__ A, const bfu* __restrict__ Bt,
    const float* __restrict__ bo, float* __restrict__ out)
{
    __shared__ __align__(16) bfu As[128 * 32];
    __shared__ __align__(16) bfu Bs[128 * 32];
    int tid = threadIdx.x;
    int w = tid >> 6, lane = tid & 63;
    int row0 = blockIdx.y * 128;
    int col0 = blockIdx.x * 128;
    int srow = lane >> 2, scg = lane & 3;

    f32x4 acc[4][4];
    #pragma unroll
    for (int i = 0; i < 4; i++)
        #pragma unroll
        for (int j = 0; j < 4; j++)
            acc[i][j] = (f32x4){0.f, 0.f, 0.f, 0.f};

    int wm = (w >> 1) * 64, wn = (w & 1) * 64;
    int l15 = lane & 15, lk = lane >> 4;

    for (int k0 = 0; k0 < 1024; k0 += 32) {
        #pragma unroll
        for (int i = 0; i < 2; i++) {
            int r = w * 32 + i * 16 + srow;
            int cg = scg ^ ((r >> 1) & 3);
            gload_lds16(A  + (size_t)(row0 + r) * 1024 + k0 + cg * 8, &As[(w * 32 + i * 16) * 32]);
            gload_lds16(Bt + (size_t)(col0 + r) * 1024 + k0 + cg * 8, &Bs[(w * 32 + i * 16) * 32]);
        }
        __syncthreads();
        short8 a[4], b[4];
        #pragma unroll
        for (int mi = 0; mi < 4; mi++) {
            int r = wm + mi * 16 + l15;
            int cs = lk ^ ((r >> 1) & 3);
            a[mi] = *reinterpret_cast<const short8*>(&As[r * 32 + cs * 8]);
        }
        #pragma unroll
        for (int ni = 0; ni < 4; ni++) {
            int r = wn + ni * 16 + l15;
            int cs = lk ^ ((r >> 1) & 3);
            b[ni] = *reinterpret_cast<const short8*>(&Bs[r * 32 + cs * 8]);
        }
        #pragma unroll
        for (int mi = 0; mi < 4; mi++)
            #pragma unroll
            for (int ni = 0; ni < 4; ni++)
                acc[mi][ni] = __builtin_amdgcn_mfma_f32_16x16x32_bf16(a[mi], b[ni], acc[mi][ni], 0, 0, 0);
        __syncthreads();
    }

    #pragma unroll
    for (int ni = 0; ni < 4; ni++) {
        int n = col0 + wn + ni * 16 + l15;
        float bb = bo[n];
        #pragma unroll
        for (int mi = 0; mi < 4; mi++) {
            #pragma unroll
            for (int r = 0; r < 4; r++) {
                int row = row0 + wm + mi * 16 + lk * 4 + r;
                out[(size_t)row * 1024 + n] = acc[mi][ni][r] + bb;
            }
        }
    }
}

// ---------------- all-level coarsen: q,k row-major pyramid; v TRANSPOSED pyramid (vcT[bh][d][sc]) ----------------
__global__ __launch_bounds__(256) void coarsen_all_kernel(
    const bfu* __restrict__ q, const bfu* __restrict__ k, const bfu* __restrict__ vt,
    bfu* __restrict__ qc, bfu* __restrict__ kc, bfu* __restrict__ vct)
{
    int bid = blockIdx.x;              // sel*4096 + bh*64 + g0
    int sel = bid >> 12;
    int bh = (bid >> 6) & 63;
    int g0 = bid & 63;
    __shared__ float bufA[64 * 64];
    __shared__ float bufB[32 * 64];
    int tid = threadIdx.x;
    const size_t GOFFc[7] = {0, 0, 8388608, 12582912, 14680064, 15728640, 16252928};
    if (sel < 2) {
        const bfu* in = sel == 0 ? q : k;
        bfu* outb     = sel == 0 ? qc : kc;
        const bfu* src = in + ((size_t)bh * SS + g0 * 64) * 64;
        for (int idx = tid; idx < 512; idx += 256) {
            int r = idx >> 3, c8 = (idx & 7) * 8;
            BF8 a; a.u4 = *reinterpret_cast<const uint4*>(src + (size_t)r * 64 + c8);
            #pragma unroll
            for (int t = 0; t < 8; t++) bufA[r * 64 + c8 + t] = bf2f(a.h[t]);
        }
        __syncthreads();
        #pragma unroll
        for (int l = 1; l <= 6; l++) {
            int nr = 64 >> l;
            float* s   = (l & 1) ? bufA : bufB;
            float* dst = (l & 1) ? bufB : bufA;
            for (int idx = tid; idx < nr * 64; idx += 256) {
                int r = idx >> 6, d = idx & 63;
                float m = 0.5f * (s[(2 * r) * 64 + d] + s[(2 * r + 1) * 64 + d]);
                dst[r * 64 + d] = m;
                outb[GOFFc[l] + ((size_t)bh * (SS >> l) + g0 * nr + r) * 64 + d] = f2bf(m);
            }
            __syncthreads();
        }
    } else {
        // transposed path: bufA layout [d][s]
        const bfu* src = vt + (size_t)bh * 64 * SS + g0 * 64;
        for (int idx = tid; idx < 512; idx += 256) {
            int d = idx >> 3, c8 = (idx & 7) * 8;
            BF8 a; a.u4 = *reinterpret_cast<const uint4*>(src + (size_t)d * SS + c8);
            #pragma unroll
            for (int t = 0; t < 8; t++) bufA[d * 64 + c8 + t] = bf2f(a.h[t]);
        }
        __syncthreads();
        #pragma unroll
        for (int l = 1; l <= 6; l++) {
            int nr = 64 >> l;               // coarse rows this level in this block
            float* s   = (l & 1) ? bufA : bufB;
            float* dst = (l & 1) ? bufB : bufA;
            for (int idx = tid; idx < (nr << 6); idx += 256) {
                int d = idx >> (6 - l);
                int r = idx & (nr - 1);
                float m = 0.5f * (s[(d << (7 - l)) + 2 * r] + s[(d << (7 - l)) + 2 * r + 1]);
                dst[(d << (6 - l)) + r] = m;
                vct[GOFFc[l] + ((size_t)bh * 64 + d) * (SS >> l) + (size_t)g0 * nr + r] = f2bf(m);
            }
            __syncthreads();
        }
    }
}

// ---------------- maxpass: wave-per-32x32-block, MFMA QK^T, no sim storage ----------------
__global__ __launch_bounds__(256) void maxpass_kernel(
    const bfu* __restrict__ q, const bfu* __restrict__ k,
    const bfu* __restrict__ qc, const bfu* __restrict__ kc,
    const float* __restrict__ rpb, unsigned* __restrict__ m_enc)
{
    const size_t GOFF[7] = {0, 0, 8388608, 12582912, 14680064, 15728640, 16252928};
    __shared__ float biasw[4][128];
    int tid = threadIdx.x, wid = tid >> 6, lane = tid & 63;
    int task = blockIdx.x * 4 + wid;     // 16256 tasks
    const bfu *qb, *kb; const float* rp; int boff, bh;
    if (task < 8192) {
        int blk = task & 127; bh = task >> 7;
        qb = q + ((size_t)bh * SS + blk * 32) * 64;
        kb = k + ((size_t)bh * SS + blk * 32) * 64;
        rp = rpb; boff = 63;
    } else {
        int rem = task - 8192;
        int l = 1, cnt = 4096;
        while (rem >= cnt) { rem -= cnt; l++; cnt >>= 1; }
        int p = 64 >> l, rows = SS >> l;
        int g2 = rem % (2 * p); bh = rem / (2 * p);
        int dir = g2 & 1, g = g2 >> 1;
        qb = qc + GOFF[l] + ((size_t)bh * rows + g * 64 + dir * 32) * 64;
        kb = kc + GOFF[l] + ((size_t)bh * rows + g * 64 + (1 - dir) * 32) * 64;
        rp = rpb + (size_t)l * 127 * 16;
        boff = dir ? 31 : 95;
    }
    int h = bh & 15;
    for (int i = lane; i < 127; i += 64) biasw[wid][i] = rp[i * 16 + h];
    __syncthreads();
    int l15 = lane & 15, lk = lane >> 4;
    f32x4 accs[2][2];
    #pragma unroll
    for (int i = 0; i < 2; i++)
        #pragma unroll
        for (int j = 0; j < 2; j++)
            accs[i][j] = (f32x4){0.f, 0.f, 0.f, 0.f};
    #pragma unroll
    for (int ks = 0; ks < 2; ks++) {
        short8 af[2], bf[2];
        #pragma unroll
        for (int mi = 0; mi < 2; mi++)
            af[mi] = *reinterpret_cast<const short8*>(kb + (size_t)(mi * 16 + l15) * 64 + ks * 32 + lk * 8);
        #pragma unroll
        for (int ni = 0; ni < 2; ni++)
            bf[ni] = *reinterpret_cast<const short8*>(qb + (size_t)(ni * 16 + l15) * 64 + ks * 32 + lk * 8);
        #pragma unroll
        for (int mi = 0; mi < 2; mi++)
            #pragma unroll
            for (int ni = 0; ni < 2; ni++)
                accs[mi][ni] = __builtin_amdgcn_mfma_f32_16x16x32_bf16(af[mi], bf[ni], accs[mi][ni], 0, 0, 0);
    }
    float lmax = -1e30f;
    #pragma unroll
    for (int mi = 0; mi < 2; mi++) {
        int kjb = mi * 16 + lk * 4;
        #pragma unroll
        for (int ni = 0; ni < 2; ni++) {
            int qi = ni * 16 + l15;
            int bidx = kjb - qi + boff;
            #pragma unroll
            for (int r = 0; r < 4; r++)
                lmax = fmaxf(lmax, accs[mi][ni][r] + biasw[wid][bidx + r]);
        }
    }
    #pragma unroll
    for (int off = 1; off < 64; off <<= 1) lmax = fmaxf(lmax, __shfl_xor(lmax, off));
    if (lane == 0) atomicMax(&m_enc[bh], encf(lmax));
}

// ---------------- pvcall: all levels, MFMA QK^T + exp + MFMA PV -> coarse yc/zc ----------------
__global__ __launch_bounds__(256) void pvcall_kernel(
    const bfu* __restrict__ qc, const bfu* __restrict__ kc, const bfu* __restrict__ vct,
    const float* __restrict__ rpb, const unsigned* __restrict__ m_enc,
    float* __restrict__ yc1, float* __restrict__ ycB, float* __restrict__ zcb)
{
    const size_t GOFF[7] = {0, 0, 8388608, 12582912, 14680064, 15728640, 16252928};
    const size_t YO[7]   = {0, 0, 0, 4194304, 6291456, 7340032, 7864320};
    const size_t ZO[7]   = {0, 0, 131072, 196608, 229376, 245760, 253952};
    __shared__ float biasw[4][128];
    __shared__ __align__(16) bfu plds[4][1280];   // 32 rows x 40 bf16 (80B stride)
    int tid = threadIdx.x, wid = tid >> 6, lane = tid & 63;
    int task = blockIdx.x * 4 + wid;     // 8064 tasks
    int rem = task;
    int l = 1, cnt = 4096;
    while (rem >= cnt) { rem -= cnt; l++; cnt >>= 1; }
    int p = 64 >> l, rows = SS >> l;
    int g2 = rem % (2 * p); int bh = rem / (2 * p);
    int dir = g2 & 1, g = g2 >> 1;
    int h = bh & 15;
    float m = 3.0f * decf(m_enc[bh]);
    const bfu* qb = qc + GOFF[l] + ((size_t)bh * rows + g * 64 + dir * 32) * 64;
    const bfu* kb = kc + GOFF[l] + ((size_t)bh * rows + g * 64 + (1 - dir) * 32) * 64;
    const bfu* vtb = vct + GOFF[l] + (size_t)bh * 64 * rows + (g * 64 + (1 - dir) * 32);
    const float* rp = rpb + (size_t)l * 127 * 16;
    int boff = dir ? 31 : 95;
    float* yc = (l == 1) ? (yc1 + (size_t)bh * 2048 * 64)
                         : (ycB + YO[l] + (size_t)bh * rows * 64);
    float* zc = zcb + ZO[l] + (size_t)bh * rows;
    int cr0 = g * 64 + dir * 32;

    for (int i = lane; i < 127; i += 64) biasw[wid][i] = rp[i * 16 + h];
    __syncthreads();
    int l15 = lane & 15, lk = lane >> 4;
    f32x4 accs[2][2];
    #pragma unroll
    for (int i = 0; i < 2; i++)
        #pragma unroll
        for (int j = 0; j < 2; j++)
            accs[i][j] = (f32x4){0.f, 0.f, 0.f, 0.f};
    #pragma unroll
    for (int ks = 0; ks < 2; ks++) {
        short8 af[2], bf[2];
        #pragma unroll
        for (int mi = 0; mi < 2; mi++)
            af[mi] = *reinterpret_cast<const short8*>(kb + (size_t)(mi * 16 + l15) * 64 + ks * 32 + lk * 8);
        #pragma unroll
        for (int ni = 0; ni < 2; ni++)
            bf[ni] = *reinterpret_cast<const short8*>(qb + (size_t)(ni * 16 + l15) * 64 + ks * 32 + lk * 8);
        #pragma unroll
        for (int mi = 0; mi < 2; mi++)
            #pragma unroll
            for (int ni = 0; ni < 2; ni++)
                accs[mi][ni] = __builtin_amdgcn_mfma_f32_16x16x32_bf16(af[mi], bf[ni], accs[mi][ni], 0, 0, 0);
    }
    // exp -> bf16 P^T in LDS; z partials from the bf16-rounded values
    float zpart0 = 0.f, zpart1 = 0.f;
    char* pb = (char*)&plds[wid][0];
    #pragma unroll
    for (int mi = 0; mi < 2; mi++) {
        int kjb = mi * 16 + lk * 4;
        #pragma unroll
        for (int ni = 0; ni < 2; ni++) {
            int qi = ni * 16 + l15;
            int bidx = kjb - qi + boff;
            bfu b0 = f2bf(expf(accs[mi][ni][0] + biasw[wid][bidx]     - m));
            bfu b1 = f2bf(expf(accs[mi][ni][1] + biasw[wid][bidx + 1] - m));
            bfu b2 = f2bf(expf(accs[mi][ni][2] + biasw[wid][bidx + 2] - m));
            bfu b3 = f2bf(expf(accs[mi][ni][3] + biasw[wid][bidx + 3] - m));
            float zs = bf2f(b0) + bf2f(b1) + bf2f(b2) + bf2f(b3);
            if (ni == 0) zpart0 += zs; else zpart1 += zs;
            *(unsigned*)(pb + qi * 80 + kjb * 2)     = (unsigned)b0 | ((unsigned)b1 << 16);
            *(unsigned*)(pb + qi * 80 + kjb * 2 + 4) = (unsigned)b2 | ((unsigned)b3 << 16);
        }
    }
    float z0 = zpart0; z0 += __shfl_xor(z0, 16); z0 += __shfl_xor(z0, 32);
    float z1 = zpart1; z1 += __shfl_xor(z1, 16); z1 += __shfl_xor(z1, 32);
    if (lane < 16) { zc[cr0 + lane] = z0; zc[cr0 + 16 + lane] = z1; }
    __syncthreads();
    // PV: A = P rows (from LDS), B = V^T cols (from global)
    short8 pa0 = *reinterpret_cast<const short8*>(pb + (size_t)l15 * 80 + lk * 16);
    short8 pa1 = *reinterpret_cast<const short8*>(pb + (size_t)(16 + l15) * 80 + lk * 16);
    f32x4 acco[2][4];
    #pragma unroll
    for (int i = 0; i < 2; i++)
        #pragma unroll
        for (int j = 0; j < 4; j++)
            acco[i][j] = (f32x4){0.f, 0.f, 0.f, 0.f};
    #pragma unroll
    for (int di = 0; di < 4; di++) {
        short8 vb8 = *reinterpret_cast<const short8*>(vtb + (size_t)(di * 16 + l15) * rows + lk * 8);
        acco[0][di] = __builtin_amdgcn_mfma_f32_16x16x32_bf16(pa0, vb8, acco[0][di], 0, 0, 0);
        acco[1][di] = __builtin_amdgcn_mfma_f32_16x16x32_bf16(pa1, vb8, acco[1][di], 0, 0, 0);
    }
    #pragma unroll
    for (int pi = 0; pi < 2; pi++)
        #pragma unroll
        for (int di = 0; di < 4; di++)
            #pragma unroll
            for (int r = 0; r < 4; r++) {
                int qi = pi * 16 + lk * 4 + r;
                int d = di * 16 + l15;
                yc[(size_t)(cr0 + qi) * 64 + d] = acco[pi][di][r];
            }
}

// ---------------- gather: level-0 MFMA sim+PV + coarse add + normalize -> bf16 A ----------------
__global__ __launch_bounds__(256) void gather_kernel(
    const bfu* __restrict__ q, const bfu* __restrict__ k, const bfu* __restrict__ vt,
    const float* __restrict__ rpb, const unsigned* __restrict__ m_enc,
    const float* __restrict__ yc1, const float* __restrict__ ycB,
    const float* __restrict__ zcb, bfu* __restrict__ yA)
{
    __shared__ float biasw[4][128];
    __shared__ __align__(16) bfu plds[4][1280];
    __shared__ float ycL[4][32][64];
    __shared__ float zcL[4][32];
    __shared__ float zrowL[4][32];
    int tid = threadIdx.x, wid = tid >> 6, lane = tid & 63;
    int task = blockIdx.x * 4 + wid;     // 8192 tasks
    int blk = task & 127, bh = task >> 7;
    int h = bh & 15;
    float m = 3.0f * decf(m_enc[bh]);
    const bfu* qb = q + ((size_t)bh * SS + blk * 32) * 64;
    const bfu* kb = k + ((size_t)bh * SS + blk * 32) * 64;
    const bfu* vtb = vt + (size_t)bh * 64 * SS + blk * 32;

    for (int i = lane; i < 127; i += 64) biasw[wid][i] = rpb[i * 16 + h];
    // stage coarse y/z rows for this 32-row block
    {
        const float* ybase[6];
        ybase[0] = yc1 + (size_t)bh * 2048 * 64;
        ybase[1] = ycB + 0       + (size_t)bh * 1024 * 64;
        ybase[2] = ycB + 4194304 + (size_t)bh * 512 * 64;
        ybase[3] = ycB + 6291456 + (size_t)bh * 256 * 64;
        ybase[4] = ycB + 7340032 + (size_t)bh * 128 * 64;
        ybase[5] = ycB + 7864320 + (size_t)bh * 64 * 64;
        const float* zbase[6];
        zbase[0] = zcb + 0      + (size_t)bh * 2048;
        zbase[1] = zcb + 131072 + (size_t)bh * 1024;
        zbase[2] = zcb + 196608 + (size_t)bh * 512;
        zbase[3] = zcb + 229376 + (size_t)bh * 256;
        zbase[4] = zcb + 245760 + (size_t)bh * 128;
        zbase[5] = zcb + 253952 + (size_t)bh * 64;
        const int Pl[6] = {0, 16, 24, 28, 30, 31};
        const int nl[6] = {16, 8, 4, 2, 1, 1};
        #pragma unroll
        for (int lvl = 1; lvl <= 6; lvl++) {
            int base_cr = (blk * 32) >> lvl;
            int cnt = nl[lvl - 1] * 64;
            for (int idx = lane; idx < cnt; idx += 64) {
                int rr = idx >> 6, dd = idx & 63;
                ycL[wid][Pl[lvl - 1] + rr][dd] = ybase[lvl - 1][(size_t)(base_cr + rr) * 64 + dd];
            }
            if (lane < nl[lvl - 1]) zcL[wid][Pl[lvl - 1] + lane] = zbase[lvl - 1][base_cr + lane];
        }
    }
    __syncthreads();
    int l15 = lane & 15, lk = lane >> 4;
    f32x4 accs[2][2];
    #pragma unroll
    for (int i = 0; i < 2; i++)
        #pragma unroll
        for (int j = 0; j < 2; j++)
            accs[i][j] = (f32x4){0.f, 0.f, 0.f, 0.f};
    #pragma unroll
    for (int ks = 0; ks < 2; ks++) {
        short8 af[2], bf[2];
        #pragma unroll
        for (int mi = 0; mi < 2; mi++)
            af[mi] = *reinterpret_cast<const short8*>(kb + (size_t)(mi * 16 + l15) * 64 + ks * 32 + lk * 8);
        #pragma unroll
        for (int ni = 0; ni < 2; ni++)
            bf[ni] = *reinterpret_cast<const short8*>(qb + (size_t)(ni * 16 + l15) * 64 + ks * 32 + lk * 8);
        #pragma unroll
        for (int mi = 0; mi < 2; mi++)
            #pragma unroll
            for (int ni = 0; ni < 2; ni++)
                accs[mi][ni] = __builtin_amdgcn_mfma_f32_16x16x32_bf16(af[mi], bf[ni], accs[mi][ni], 0, 0, 0);
    }
    float zpart0 = 0.f, zpart1 = 0.f;
    char* pb = (char*)&plds[wid][0];
    #pragma unroll
    for (int mi = 0; mi < 2; mi++) {
        int kjb = mi * 16 + lk * 4;
        #pragma unroll
        for (int ni = 0; ni < 2; ni++) {
            int qi = ni * 16 + l15;
            int bidx = kjb - qi + 63;
            bfu b0 = f2bf(expf(accs[mi][ni][0] + biasw[wid][bidx]     - m));
            bfu b1 = f2bf(expf(accs[mi][ni][1] + biasw[wid][bidx + 1] - m));
            bfu b2 = f2bf(expf(accs[mi][ni][2] + biasw[wid][bidx + 2] - m));
            bfu b3 = f2bf(expf(accs[mi][ni][3] + biasw[wid][bidx + 3] - m));
            float zs = bf2f(b0) + bf2f(b1) + bf2f(b2) + bf2f(b3);
            if (ni == 0) zpart0 += zs; else zpart1 += zs;
            *(unsigned*)(pb + qi * 80 + kjb * 2)     = (unsigned)b0 | ((unsigned)b1 << 16);
            *(unsigned*)(pb + qi * 80 + kjb * 2 + 4) = (unsigned)b2 | ((unsigned)b3 << 16);
        }
    }
    float z0 = zpart0; z0 += __shfl_xor(z0, 16); z0 += __shfl_xor(z0, 32);
    float z1 = zpart1; z1 += __shfl_xor(z1, 16); z1 += __shfl_xor(z1, 32);
    {
        const int Pl[6] = {0, 16, 24, 28, 30, 31};
        if (lane < 16) {
            float zs0 = z0, zs1 = z1;
            #pragma unroll
            for (int lvl = 1; lvl <= 6; lvl++) {
                zs0 += zcL[wid][Pl[lvl - 1] + (lane >> lvl)];
                zs1 += zcL[wid][Pl[lvl - 1] + ((16 + lane) >> lvl)];
            }
            zrowL[wid][lane] = 1.0f / zs0;
            zrowL[wid][16 + lane] = 1.0f / zs1;
        }
    }
    __syncthreads();
    short8 pa0 = *reinterpret_cast<const short8*>(pb + (size_t)l15 * 80 + lk * 16);
    short8 pa1 = *reinterpret_cast<const short8*>(pb + (size_t)(16 + l15) * 80 + lk * 16);
    f32x4 acco[2][4];
    #pragma unroll
    for (int i = 0; i < 2; i++)
        #pragma unroll
        for (int j = 0; j < 4; j++)
            acco[i][j] = (f32x4){0.f, 0.f, 0.f, 0.f};
    #pragma unroll
    for (int di = 0; di < 4; di++) {
        short8 vb8 = *reinterpret_cast<const short8*>(vtb + (size_t)(di * 16 + l15) * SS + lk * 8);
        acco[0][di] = __builtin_amdgcn_mfma_f32_16x16x32_bf16(pa0, vb8, acco[0][di], 0, 0, 0);
        acco[1][di] = __builtin_amdgcn_mfma_f32_16x16x32_bf16(pa1, vb8, acco[1][di], 0, 0, 0);
    }
    const int Pl[6] = {0, 16, 24, 28, 30, 31};
    int b = bh >> 4, s0 = blk * 32;
    #pragma unroll
    for (int pi = 0; pi < 2; pi++)
        #pragma unroll
        for (int di = 0; di < 4; di++)
            #pragma unroll
            for (int r = 0; r < 4; r++) {
                int qi = pi * 16 + lk * 4 + r;
                int d = di * 16 + l15;
                float o = acco[pi][di][r];
                #pragma unroll
                for (int lvl = 1; lvl <= 6; lvl++)
                    o += ycL[wid][Pl[lvl - 1] + (qi >> lvl)][d];
                o *= zrowL[wid][qi];
                yA[((size_t)(b * SS + s0 + qi)) * 1024 + h * 64 + d] = f2bf(o);
            }
}

extern "C" void kernel_launch(void* const* d_in, const int* in_sizes, int n_in,
                              void* d_out, int out_size, void* d_ws, size_t ws_size,
                              hipStream_t stream)
{
    const float* x   = (const float*)d_in[0];
    const float* wq  = (const float*)d_in[1];
    const float* bq  = (const float*)d_in[2];
    const float* wk  = (const float*)d_in[3];
    const float* bk  = (const float*)d_in[4];
    const float* wv  = (const float*)d_in[5];
    const float* bv  = (const float*)d_in[6];
    const float* rpb = (const float*)d_in[7];
    const float* wo  = (const float*)d_in[8];
    const float* bo  = (const float*)d_in[9];
    float* out = (float*)d_out;

    const size_t NEED = 267387392ULL;   // 255.0 MiB
    if (ws_size < NEED) {
        float val = (float)(ws_size >> 20);
        int n = out_size;
        hipLaunchKernelGGL(diag_kernel, dim3((n + 255) / 256), dim3(256), 0, stream, out, val, n);
        return;
    }

    char* w8 = (char*)d_ws;
    bfu* q    = (bfu*)(w8);                        // 32 MiB, live until gather
    bfu* k    = (bfu*)(w8 + 33554432);             // 32 MiB, live until gather
    bfu* vt   = (bfu*)(w8 + 67108864);             // 32 MiB, V^T [bh][64][4096], live until gather
    bfu* qc   = (bfu*)(w8 + 100663296);            // 31.5 MiB, dead after pvcall -> yA
    bfu* kc   = (bfu*)(w8 + 133693440);            // 31.5 MiB, dead after pvcall -> wot (at +1.5MiB)
    bfu* vct  = (bfu*)(w8 + 166723584);            // 31.5 MiB, V^T pyramid [bh][64][S>>l]
    // region A (32 MiB): xbf (stages 1-2) then ycB + zcb
    // region B (32 MiB): wqkv_t (stages 1-2) then yc1
    bfu*   xbf    = (bfu*)(w8 + 199753728);
    bfu*   wqkv_t = (bfu*)(w8 + 233308160);
    float* ycB    = (float*)(w8 + 199753728);      // 32,505,856 B (levels 2-6)
    float* zcb    = (float*)(w8 + 232259584);      //  1,048,576 B (all levels z)
    float* yc1    = (float*)(w8 + 233308160);      // 33,554,432 B (level 1)
    unsigned* m_enc = (unsigned*)(w8 + 266862592);
    bfu*   yA     = qc;                            // 32 MiB over dead qc (+0.5 MiB into kc)
    bfu*   wot    = (bfu*)(w8 + 135266304);        // 2 MiB in dead kc slot, past yA spill

    // 1. bf16 conversions: x, transposed weights [N][K]
    hipLaunchKernelGGL(f32_to_bf16_kernel, dim3(8192), dim3(256), 0, stream, x, xbf, 2097152);
    hipLaunchKernelGGL(transpose_w_kernel, dim3(32, 32), dim3(256), 0, stream, wq, wqkv_t);
    hipLaunchKernelGGL(transpose_w_kernel, dim3(32, 32), dim3(256), 0, stream, wk, wqkv_t + 1048576);
    hipLaunchKernelGGL(transpose_w_kernel, dim3(32, 32), dim3(256), 0, stream, wv, wqkv_t + 2097152);

    // 2. QKV projection (bf16 MFMA; v written transposed)
    hipLaunchKernelGGL(gemm_qkv_mfma, dim3(24, 128), dim3(256), 0, stream,
                       xbf, wqkv_t, bq, bk, bv, q, k, vt);

    // 3. coarsen pyramid (q,k row-major; v transposed)
    hipLaunchKernelGGL(coarsen_all_kernel, dim3(12288), dim3(256), 0, stream, q, k, vt, qc, kc, vct);

    // 4. global max over all levels (MFMA, no sim storage)
    hipMemsetAsync(m_enc, 0, 256, stream);
    hipLaunchKernelGGL(maxpass_kernel, dim3(4064), dim3(256), 0, stream, q, k, qc, kc, rpb, m_enc);

    // 5. all-level sim-recompute + PV -> coarse yc/zc (MFMA, one launch)
    hipLaunchKernelGGL(pvcall_kernel, dim3(2016), dim3(256), 0, stream,
                       qc, kc, vct, rpb, m_enc, yc1, ycB, zcb);

    // 6. transpose Wo into dead kc slot
    hipLaunchKernelGGL(transpose_w_kernel, dim3(32, 32), dim3(256), 0, stream, wo, wot);

    // 7. fused level-0 sim + PV + coarse gather + normalize -> bf16 A (over dead qc)
    hipLaunchKernelGGL(gather_kernel, dim3(2048), dim3(256), 0, stream,
                       q, k, vt, rpb, m_enc, yc1, ycB, zcb, yA);

    // 8. output projection (bf16 MFMA)
    hipLaunchKernelGGL(gemm_out_mfma, dim3(8, 128), dim3(256), 0, stream, yA, wot, bo, out);
}